// Round 1
// baseline (12.898 us; speedup 1.0000x reference)
//
#include <hip/hip_runtime.h>

#define EOS_TOKEN 1

__global__ __launch_bounds__(512) void nll_per_seq_kernel(
    const float* __restrict__ input,   // [B, S, V] log-probs
    const int*   __restrict__ target,  // [B, S]
    float*       __restrict__ per_seq, // [B] scratch
    int S, int V)
{
    const int b = blockIdx.x;
    const int s = threadIdx.x;          // one thread per token position

    __shared__ int   s_eos;
    __shared__ float s_wsum[8];         // 512 threads = 8 waves

    if (threadIdx.x == 0) s_eos = S;    // sentinel larger than any index
    __syncthreads();

    const int t = target[(size_t)b * S + s];
    if (t == EOS_TOKEN) atomicMin(&s_eos, s);
    __syncthreads();

    const int eos = s_eos;              // first EOS position (>=1 by construction)

    float v = 0.0f;
    if (s <= eos) {
        v = input[((size_t)b * S + s) * (size_t)V + (size_t)t];
    }

    // 64-lane wave reduction
    #pragma unroll
    for (int off = 32; off > 0; off >>= 1)
        v += __shfl_down(v, off, 64);

    const int lane = threadIdx.x & 63;
    const int wid  = threadIdx.x >> 6;
    if (lane == 0) s_wsum[wid] = v;
    __syncthreads();

    if (threadIdx.x == 0) {
        float sum = 0.0f;
        #pragma unroll
        for (int w = 0; w < 8; ++w) sum += s_wsum[w];
        per_seq[b] = -sum / (float)eos;
    }
}

__global__ void nll_final_kernel(const float* __restrict__ per_seq,
                                 float* __restrict__ out, int B)
{
    if (threadIdx.x == 0 && blockIdx.x == 0) {
        float sum = 0.0f;
        for (int i = 0; i < B; ++i) sum += per_seq[i];
        out[0] = sum;   // overwrite: deterministic, no cross-call state
    }
}

extern "C" void kernel_launch(void* const* d_in, const int* in_sizes, int n_in,
                              void* d_out, int out_size, void* d_ws, size_t ws_size,
                              hipStream_t stream)
{
    const float* input  = (const float*)d_in[0];
    const int*   target = (const int*)d_in[1];
    float*       out    = (float*)d_out;
    float*       ws     = (float*)d_ws;

    const int S  = 512;
    const int BS = in_sizes[1];          // B*S
    const int B  = BS / S;
    const int V  = (int)((long long)in_sizes[0] / (long long)BS);

    nll_per_seq_kernel<<<B, S, 0, stream>>>(input, target, ws, S, V);
    nll_final_kernel<<<1, 64, 0, stream>>>(ws, out, B);
}

// Round 2
// 11.293 us; speedup vs baseline: 1.1421x; 1.1421x over previous
//
#include <hip/hip_runtime.h>

#define EOS_TOKEN 1

// One block, 1024 threads. B=8, S=512 => 4096 tokens, 4 per thread.
__global__ __launch_bounds__(1024) void nll_fused_kernel(
    const float* __restrict__ input,   // [B, S, V] log-probs
    const int*   __restrict__ target,  // [B, S]
    float*       __restrict__ out,     // [1]
    int B, int S, int V)
{
    const int tid = threadIdx.x;
    const int TOT = B * S;             // 4096

    __shared__ int   s_eos[32];        // B <= 32
    __shared__ float s_inv[32];
    __shared__ float s_wsum[16];       // 1024 threads = 16 waves

    if (tid < B) s_eos[tid] = S;       // sentinel
    __syncthreads();

    // Phase 1: load targets (coalesced), find first EOS per sequence.
    int tgt[4];
    int idxv[4];
    #pragma unroll
    for (int i = 0; i < 4; ++i) {
        const int idx = tid + i * 1024;
        idxv[i] = idx;
        tgt[i]  = (idx < TOT) ? target[idx] : 0;
        if (idx < TOT && tgt[i] == EOS_TOKEN)
            atomicMin(&s_eos[idx / S], idx % S);
    }
    __syncthreads();

    if (tid < B) s_inv[tid] = 1.0f / (float)s_eos[tid];
    __syncthreads();

    // Phase 2: gather log p(target) for masked tokens, accumulate -lp/eos.
    float acc = 0.0f;
    #pragma unroll
    for (int i = 0; i < 4; ++i) {
        const int idx = idxv[i];
        if (idx < TOT) {
            const int b = idx / S;
            const int s = idx % S;
            if (s <= s_eos[b]) {
                const float lp = input[(size_t)idx * (size_t)V + (size_t)tgt[i]];
                acc -= lp * s_inv[b];
            }
        }
    }

    // Phase 3: block reduction (64-lane shuffle, then cross-wave LDS).
    #pragma unroll
    for (int off = 32; off > 0; off >>= 1)
        acc += __shfl_down(acc, off, 64);

    const int lane = tid & 63;
    const int wid  = tid >> 6;
    if (lane == 0) s_wsum[wid] = acc;
    __syncthreads();

    if (tid == 0) {
        float sum = 0.0f;
        #pragma unroll
        for (int w = 0; w < 16; ++w) sum += s_wsum[w];
        out[0] = sum;                  // overwrite: deterministic each call
    }
}

extern "C" void kernel_launch(void* const* d_in, const int* in_sizes, int n_in,
                              void* d_out, int out_size, void* d_ws, size_t ws_size,
                              hipStream_t stream)
{
    const float* input  = (const float*)d_in[0];
    const int*   target = (const int*)d_in[1];
    float*       out    = (float*)d_out;

    const int S  = 512;
    const int BS = in_sizes[1];          // B*S
    const int B  = BS / S;
    const int V  = (int)((long long)in_sizes[0] / (long long)BS);

    nll_fused_kernel<<<1, 1024, 0, stream>>>(input, target, out, B, S, V);
}

// Round 3
// 9.555 us; speedup vs baseline: 1.3498x; 1.1818x over previous
//
#include <hip/hip_runtime.h>

#define EOS_TOKEN 1

// One block, 1024 threads. B=8, S=512 => 4096 tokens, 4 per thread.
// Gathers are issued unconditionally right after targets arrive; the EOS
// search and masking overlap with gather latency.
__global__ __launch_bounds__(1024) void nll_fused_kernel(
    const float* __restrict__ input,   // [B, S, V] log-probs
    const int*   __restrict__ target,  // [B, S]
    float*       __restrict__ out,     // [1]
    int B, int S, int V)
{
    const int tid = threadIdx.x;
    const int TOT = B * S;             // 4096

    __shared__ int   s_eos[32];        // B <= 32
    __shared__ float s_inv[32];
    __shared__ float s_wsum[16];       // 1024 threads = 16 waves

    if (tid < B) s_eos[tid] = S;       // sentinel
    __syncthreads();

    // Phase 1: coalesced target loads (each thread's own 4 tokens).
    int tgt[4];
    #pragma unroll
    for (int i = 0; i < 4; ++i) {
        const int idx = tid + i * 1024;
        tgt[i] = (idx < TOT) ? target[idx] : 2;
    }

    // Phase 2: issue ALL gathers now (addresses independent of EOS; ids are
    // valid for every token). These stay in flight during phase 3.
    float lp[4];
    #pragma unroll
    for (int i = 0; i < 4; ++i) {
        const int idx = tid + i * 1024;
        lp[i] = (idx < TOT) ? input[(size_t)idx * (size_t)V + (size_t)tgt[i]]
                            : 0.0f;
    }

    // Phase 3: EOS search from registers (overlaps gather latency).
    #pragma unroll
    for (int i = 0; i < 4; ++i) {
        const int idx = tid + i * 1024;
        if (idx < TOT && tgt[i] == EOS_TOKEN)
            atomicMin(&s_eos[idx / S], idx % S);
    }
    __syncthreads();

    if (tid < B) s_inv[tid] = 1.0f / (float)s_eos[tid];
    __syncthreads();

    // Phase 4: masked accumulate (vmcnt wait lands here).
    float acc = 0.0f;
    #pragma unroll
    for (int i = 0; i < 4; ++i) {
        const int idx = tid + i * 1024;
        if (idx < TOT) {
            const int b = idx / S;
            const int s = idx % S;
            if (s <= s_eos[b]) acc -= lp[i] * s_inv[b];
        }
    }

    // Phase 5: block reduction (64-lane shuffle, then cross-wave LDS).
    #pragma unroll
    for (int off = 32; off > 0; off >>= 1)
        acc += __shfl_down(acc, off, 64);

    const int lane = tid & 63;
    const int wid  = tid >> 6;
    if (lane == 0) s_wsum[wid] = acc;
    __syncthreads();

    if (tid == 0) {
        float sum = 0.0f;
        #pragma unroll
        for (int w = 0; w < 16; ++w) sum += s_wsum[w];
        out[0] = sum;                  // overwrite: deterministic each call
    }
}

extern "C" void kernel_launch(void* const* d_in, const int* in_sizes, int n_in,
                              void* d_out, int out_size, void* d_ws, size_t ws_size,
                              hipStream_t stream)
{
    const float* input  = (const float*)d_in[0];
    const int*   target = (const int*)d_in[1];
    float*       out    = (float*)d_out;

    const int S  = 512;
    const int BS = in_sizes[1];          // B*S
    const int B  = BS / S;
    const int V  = (int)((long long)in_sizes[0] / (long long)BS);

    nll_fused_kernel<<<1, 1024, 0, stream>>>(input, target, out, B, S, V);
}